// Round 1
// baseline (738.613 us; speedup 1.0000x reference)
//
#include <hip/hip_runtime.h>
#include <hip/hip_bf16.h>

// RGCN: 3 layers of basis-decomposed relational graph conv + predictor.
// Strategy: CSR-by-dst build (per call, deterministic work), then per layer:
//   Z[n, b*64+i] = sum_{e: dst=n} comp[et_e, b] * x[src_e, i]   (wave/node)
//   out = relu([Z | x] @ [bases ; loop_w] + bias)               (tiled GEMM)
// Final: sigmoid(x @ pred_w + pred_b).

#define NODES_PER_BLOCK 4

__global__ void k_hist(const int* __restrict__ dst, int* __restrict__ deg, int E) {
  int e = blockIdx.x * blockDim.x + threadIdx.x;
  if (e < E) atomicAdd(&deg[dst[e]], 1);
}

// Single-block exclusive scan over N degrees -> row_off (N+1) and cursor (N).
// NOTE: deg may alias cursor (read v before write), so no __restrict__ here.
__global__ void __launch_bounds__(1024) k_scan(const int* deg, int* row_off,
                                               int* cursor, int N) {
  __shared__ int wsum[16];
  __shared__ int s_carry;
  int t = threadIdx.x;
  int lane = t & 63, wid = t >> 6;
  if (t == 0) s_carry = 0;
  __syncthreads();
  for (int base = 0; base < N; base += 1024) {
    int idx = base + t;
    int v = (idx < N) ? deg[idx] : 0;
    int s = v;
#pragma unroll
    for (int off = 1; off < 64; off <<= 1) {
      int u = __shfl_up(s, off, 64);
      if (lane >= off) s += u;
    }
    if (lane == 63) wsum[wid] = s;
    __syncthreads();
    if (wid == 0) {
      int ws = (lane < 16) ? wsum[lane] : 0;
#pragma unroll
      for (int off = 1; off < 16; off <<= 1) {
        int u = __shfl_up(ws, off, 64);
        if (lane >= off) ws += u;
      }
      if (lane < 16) wsum[lane] = ws;
    }
    __syncthreads();
    int carry = s_carry;
    int wave_excl = (wid == 0) ? 0 : wsum[wid - 1];
    int excl = carry + wave_excl + (s - v);
    if (idx < N) { row_off[idx] = excl; cursor[idx] = excl; }
    __syncthreads();
    if (t == 0) s_carry = carry + wsum[15];
    __syncthreads();
  }
  if (t == 0) row_off[N] = s_carry;
}

__global__ void k_fill(const int* __restrict__ src, const int* __restrict__ dst,
                       const int* __restrict__ et, int* __restrict__ cursor,
                       int* __restrict__ epk, int E) {
  int e = blockIdx.x * blockDim.x + threadIdx.x;
  if (e < E) {
    int p = atomicAdd(&cursor[dst[e]], 1);
    epk[p] = src[e] | (et[e] << 28);
  }
}

// One wave per node; lane = channel. Z[n][0..63]=basis0 acc, [64..127]=basis1.
__global__ void __launch_bounds__(256) k_aggregate(
    const float* __restrict__ x, const int* __restrict__ row_off,
    const int* __restrict__ epk, const float* __restrict__ comp,
    float* __restrict__ Z, int N) {
  __shared__ float s_comp[8];
  if (threadIdx.x < 8) s_comp[threadIdx.x] = comp[threadIdx.x];
  __syncthreads();
  int node = blockIdx.x * NODES_PER_BLOCK + (threadIdx.x >> 6);
  int lane = threadIdx.x & 63;
  if (node >= N) return;
  int beg = row_off[node], end = row_off[node + 1];
  float z0 = 0.f, z1 = 0.f;
  int e = beg;
  // 2-wide unroll: two independent load chains to hide gather latency.
  for (; e + 1 < end; e += 2) {
    int pk0 = epk[e], pk1 = epk[e + 1];
    int s0 = pk0 & 0x0FFFFFFF, r0 = (pk0 >> 28) & 3;
    int s1 = pk1 & 0x0FFFFFFF, r1 = (pk1 >> 28) & 3;
    float xv0 = x[(size_t)s0 * 64 + lane];
    float xv1 = x[(size_t)s1 * 64 + lane];
    z0 = fmaf(s_comp[r0 * 2 + 0], xv0, z0);
    z1 = fmaf(s_comp[r0 * 2 + 1], xv0, z1);
    z0 = fmaf(s_comp[r1 * 2 + 0], xv1, z0);
    z1 = fmaf(s_comp[r1 * 2 + 1], xv1, z1);
  }
  if (e < end) {
    int pk = epk[e];
    int s = pk & 0x0FFFFFFF, r = (pk >> 28) & 3;
    float xv = x[(size_t)s * 64 + lane];
    z0 = fmaf(s_comp[r * 2 + 0], xv, z0);
    z1 = fmaf(s_comp[r * 2 + 1], xv, z1);
  }
  Z[(size_t)node * 128 + lane] = z0;
  Z[(size_t)node * 128 + 64 + lane] = z1;
}

// out[n,:] = relu( Z[n,0:128] @ bases(128x64) + x[n,:] @ loop_w(64x64) + bias )
// 64-row x 64-col tile per block, 256 threads, 4x4 micro-tile per thread.
// A panel in LDS with XOR swizzle on k (key = (row>>2)&3) to kill bank
// conflicts on the per-k scalar a-reads (4 rows stride-64 -> same bank).
__global__ void __launch_bounds__(256) k_gemm(
    const float* __restrict__ Z, const float* __restrict__ x,
    const float* __restrict__ bases, const float* __restrict__ loopw,
    const float* __restrict__ bias, float* __restrict__ out, int N) {
  __shared__ float sW[64 * 64];  // current k-chunk of W: 16 KB
  __shared__ float sA[64 * 64];  // A panel (swizzled): 16 KB
  int t = threadIdx.x;
  int tx = t & 15, ty = t >> 4;
  int row0 = blockIdx.x * 64;
  float acc[4][4] = {{0.f, 0.f, 0.f, 0.f}};

  for (int ch = 0; ch < 3; ++ch) {
    __syncthreads();  // protect previous chunk's sW/sA reads
    // ---- load W chunk (rows ch*64 .. ch*64+63 of the 192x64 stacked W)
    const float4* wsrc = (ch < 2) ? ((const float4*)bases + (size_t)ch * 1024)
                                  : (const float4*)loopw;
#pragma unroll
    for (int q = 0; q < 4; ++q) ((float4*)sW)[t + q * 256] = wsrc[t + q * 256];
    // ---- load A panel: chunk0 = Z[:,0:64], chunk1 = Z[:,64:128], chunk2 = x
#pragma unroll
    for (int q = 0; q < 4; ++q) {
      int i = t + q * 256;        // float4 index within 64x64 panel
      int lr = i >> 4;            // row 0..63
      int lc = (i & 15) * 4;      // col 0,4,...,60
      int grow = row0 + lr;
      float4 v = make_float4(0.f, 0.f, 0.f, 0.f);
      if (grow < N) {
        const float* g;
        if (ch == 0)      g = Z + (size_t)grow * 128 + lc;
        else if (ch == 1) g = Z + (size_t)grow * 128 + 64 + lc;
        else              g = x + (size_t)grow * 64 + lc;
        v = *(const float4*)g;
      }
      int swc = lc ^ (((lr >> 2) & 3) << 4);
      *(float4*)(sA + lr * 64 + swc) = v;
    }
    __syncthreads();
    // ---- compute
    int swk_base = (ty & 3) << 4;  // (row>>2)&3 == ty&3 for rows ty*4+j
#pragma unroll 4
    for (int k = 0; k < 64; ++k) {
      float4 wv = *(const float4*)(sW + k * 64 + tx * 4);
      int kk = k ^ swk_base;
      float a0 = sA[(ty * 4 + 0) * 64 + kk];
      float a1 = sA[(ty * 4 + 1) * 64 + kk];
      float a2 = sA[(ty * 4 + 2) * 64 + kk];
      float a3 = sA[(ty * 4 + 3) * 64 + kk];
      acc[0][0] = fmaf(a0, wv.x, acc[0][0]);
      acc[0][1] = fmaf(a0, wv.y, acc[0][1]);
      acc[0][2] = fmaf(a0, wv.z, acc[0][2]);
      acc[0][3] = fmaf(a0, wv.w, acc[0][3]);
      acc[1][0] = fmaf(a1, wv.x, acc[1][0]);
      acc[1][1] = fmaf(a1, wv.y, acc[1][1]);
      acc[1][2] = fmaf(a1, wv.z, acc[1][2]);
      acc[1][3] = fmaf(a1, wv.w, acc[1][3]);
      acc[2][0] = fmaf(a2, wv.x, acc[2][0]);
      acc[2][1] = fmaf(a2, wv.y, acc[2][1]);
      acc[2][2] = fmaf(a2, wv.z, acc[2][2]);
      acc[2][3] = fmaf(a2, wv.w, acc[2][3]);
      acc[3][0] = fmaf(a3, wv.x, acc[3][0]);
      acc[3][1] = fmaf(a3, wv.y, acc[3][1]);
      acc[3][2] = fmaf(a3, wv.z, acc[3][2]);
      acc[3][3] = fmaf(a3, wv.w, acc[3][3]);
    }
  }
  // ---- epilogue: bias + relu, coalesced float4 store
  float4 bv = *(const float4*)(bias + tx * 4);
#pragma unroll
  for (int j = 0; j < 4; ++j) {
    int r = row0 + ty * 4 + j;
    if (r < N) {
      float4 o;
      o.x = fmaxf(acc[j][0] + bv.x, 0.f);
      o.y = fmaxf(acc[j][1] + bv.y, 0.f);
      o.z = fmaxf(acc[j][2] + bv.z, 0.f);
      o.w = fmaxf(acc[j][3] + bv.w, 0.f);
      *(float4*)(out + (size_t)r * 64 + tx * 4) = o;
    }
  }
}

__global__ void __launch_bounds__(256) k_pred(
    const float* __restrict__ x, const float* __restrict__ pw,
    const float* __restrict__ pb, float* __restrict__ out, int N) {
  int node = blockIdx.x * NODES_PER_BLOCK + (threadIdx.x >> 6);
  int lane = threadIdx.x & 63;
  if (node >= N) return;
  float v = x[(size_t)node * 64 + lane] * pw[lane];
#pragma unroll
  for (int off = 32; off > 0; off >>= 1) v += __shfl_down(v, off, 64);
  if (lane == 0) {
    float logit = v + pb[0];
    out[node] = 1.f / (1.f + expf(-logit));
  }
}

extern "C" void kernel_launch(void* const* d_in, const int* in_sizes, int n_in,
                              void* d_out, int out_size, void* d_ws, size_t ws_size,
                              hipStream_t stream) {
  const float* features = (const float*)d_in[0];
  const int* src = (const int*)d_in[1];
  const int* dst = (const int*)d_in[2];
  const int* et  = (const int*)d_in[3];
  const float* bases[3] = {(const float*)d_in[4], (const float*)d_in[8],  (const float*)d_in[12]};
  const float* comp[3]  = {(const float*)d_in[5], (const float*)d_in[9],  (const float*)d_in[13]};
  const float* loopw[3] = {(const float*)d_in[6], (const float*)d_in[10], (const float*)d_in[14]};
  const float* biasp[3] = {(const float*)d_in[7], (const float*)d_in[11], (const float*)d_in[15]};
  const float* pred_w = (const float*)d_in[16];
  const float* pred_b = (const float*)d_in[17];

  const int N = in_sizes[0] / 64;   // 100000
  const int E = in_sizes[1];        // 1600000

  // workspace layout (256B aligned slices)
  char* ws = (char*)d_ws;
  size_t off = 0;
  auto take = [&](size_t bytes) {
    char* p = ws + off;
    off += (bytes + 255) & ~(size_t)255;
    return p;
  };
  int*   row_off = (int*)  take((size_t)(N + 1) * 4);
  int*   cursor  = (int*)  take((size_t)N * 4);        // doubles as deg
  int*   epk     = (int*)  take((size_t)E * 4);
  float* Zb      = (float*)take((size_t)N * 128 * 4);
  float* xA      = (float*)take((size_t)N * 64 * 4);
  float* xB      = (float*)take((size_t)N * 64 * 4);
  (void)ws_size;

  // ---- CSR build (deterministic work; atomic fill order only perturbs
  //      fp32 summation order within a node, well inside tolerance)
  hipMemsetAsync(cursor, 0, (size_t)N * sizeof(int), stream);
  k_hist<<<(E + 255) / 256, 256, 0, stream>>>(dst, cursor, E);
  k_scan<<<1, 1024, 0, stream>>>(cursor, row_off, cursor, N);
  k_fill<<<(E + 255) / 256, 256, 0, stream>>>(src, dst, et, cursor, epk, E);

  // ---- 3 RGCN layers
  const float* xin = features;
  float* outs[3] = {xA, xB, xA};
  int agg_grid = (N + NODES_PER_BLOCK - 1) / NODES_PER_BLOCK;
  int gemm_grid = (N + 63) / 64;
  for (int l = 0; l < 3; ++l) {
    k_aggregate<<<agg_grid, 256, 0, stream>>>(xin, row_off, epk, comp[l], Zb, N);
    k_gemm<<<gemm_grid, 256, 0, stream>>>(Zb, xin, bases[l], loopw[l], biasp[l], outs[l], N);
    xin = outs[l];
  }

  // ---- predictor + sigmoid
  k_pred<<<agg_grid, 256, 0, stream>>>(xA, pred_w, pred_b, (float*)d_out, N);
}

// Round 2
// 497.179 us; speedup vs baseline: 1.4856x; 1.4856x over previous
//
#include <hip/hip_runtime.h>
#include <hip/hip_bf16.h>

// RGCN: 3 layers of basis-decomposed relational graph conv + predictor.
// CSR build via 2-level counting sort (NO global atomics):
//   L1: partition edges into 196 buckets of 512 dst-nodes (LDS hist + scan
//       matrix -> disjoint per-(block,bucket) ranges, LDS cursors).
//   L2: per-bucket 512-bin LDS sort -> exact per-node CSR + row_off.
// Per layer:
//   Z[n, b*64+i] = sum_{e: dst=n} comp[et_e, b] * x[src_e, i]   (wave/node)
//   out = relu([Z | x] @ [bases ; loop_w] + bias)               (tiled GEMM)
// Final: sigmoid(x @ pred_w + pred_b).

#define NODES_PER_BLOCK 4
#define NB1 196        // ceil(100000/512) coarse buckets
#define NBLK1 256      // L1 partition blocks
#define BUCKET_SHIFT 9 // 512 nodes per bucket

// inclusive scan of one int per thread across a 256-thread block
__device__ inline int block_incl_scan_256(int v, int* wsums) {
  int lane = threadIdx.x & 63, wid = threadIdx.x >> 6;
  int s = v;
#pragma unroll
  for (int off = 1; off < 64; off <<= 1) {
    int u = __shfl_up(s, off, 64);
    if (lane >= off) s += u;
  }
  if (lane == 63) wsums[wid] = s;
  __syncthreads();
  if (threadIdx.x == 0) {
    int a = 0;
#pragma unroll
    for (int w = 0; w < 4; ++w) { int t = wsums[w]; wsums[w] = a; a += t; }
  }
  __syncthreads();
  return s + wsums[wid];
}

// ---- L1 pass a: per-block LDS histogram over 196 coarse buckets
__global__ void __launch_bounds__(256) k_l1hist(const int* __restrict__ dst,
                                                int* __restrict__ H, int E, int chunk) {
  __shared__ int h[NB1];
  int t = threadIdx.x;
  if (t < NB1) h[t] = 0;
  __syncthreads();
  int beg = blockIdx.x * chunk;
  int end = min(beg + chunk, E);
  for (int i = beg + t; i < end; i += 256) atomicAdd(&h[dst[i] >> BUCKET_SHIFT], 1);
  __syncthreads();
  if (t < NB1) H[blockIdx.x * NB1 + t] = h[t];
}

// ---- L1 pass b: scan each bucket's column of H (256 rows) in place -> excl,
//      emit per-bucket totals
__global__ void __launch_bounds__(256) k_colscan(int* __restrict__ H,
                                                 int* __restrict__ total) {
  __shared__ int wsums[4];
  int b = blockIdx.x;
  int t = threadIdx.x;
  int v = H[t * NB1 + b];
  int s = block_incl_scan_256(v, wsums);
  H[t * NB1 + b] = s - v;
  if (t == 255) total[b] = s;
}

// ---- L1 pass c: scan bucket totals -> bucket_base[0..NB1], row_off[N]=E
__global__ void __launch_bounds__(256) k_basescan(const int* __restrict__ total,
                                                  int* __restrict__ bucket_base,
                                                  int* __restrict__ row_off, int N) {
  __shared__ int wsums[4];
  int t = threadIdx.x;
  int v = (t < NB1) ? total[t] : 0;
  int s = block_incl_scan_256(v, wsums);
  if (t < NB1) bucket_base[t] = s - v;
  if (t == 255) { bucket_base[NB1] = s; row_off[N] = s; }
}

// ---- L1 pass d: scatter edges into bucket-partitioned epk1 via LDS cursors
__global__ void __launch_bounds__(256) k_scatter1(
    const int* __restrict__ src, const int* __restrict__ dst,
    const int* __restrict__ et, const int* __restrict__ H,
    const int* __restrict__ bucket_base, int* __restrict__ epk1,
    int E, int chunk) {
  __shared__ int cur[NB1];
  int t = threadIdx.x;
  if (t < NB1) cur[t] = bucket_base[t] + H[blockIdx.x * NB1 + t];
  __syncthreads();
  int beg = blockIdx.x * chunk;
  int end = min(beg + chunk, E);
  for (int i = beg + t; i < end; i += 256) {
    int d = dst[i];
    int b = d >> BUCKET_SHIFT;
    int p = atomicAdd(&cur[b], 1);
    epk1[p] = src[i] | (et[i] << 17) | ((d & 511) << 19);
  }
}

// ---- L2: per-bucket exact sort by dst_local (512 bins) -> epk + row_off
__global__ void __launch_bounds__(256) k_bucket(
    const int* __restrict__ epk1, const int* __restrict__ bucket_base,
    int* __restrict__ epk, int* __restrict__ row_off, int N) {
  __shared__ int hist[512];
  __shared__ int cur[512];
  __shared__ int wsums[4];
  int b = blockIdx.x;
  int t = threadIdx.x;
  int ebase = bucket_base[b], eend = bucket_base[b + 1];
  hist[t] = 0; hist[t + 256] = 0;
  __syncthreads();
  for (int i = ebase + t; i < eend; i += 256) atomicAdd(&hist[epk1[i] >> 19], 1);
  __syncthreads();
  int h0 = hist[2 * t], h1 = hist[2 * t + 1];
  int pair = h0 + h1;
  int incl = block_incl_scan_256(pair, wsums);
  int e0 = incl - pair;         // excl for bin 2t
  cur[2 * t] = ebase + e0;
  cur[2 * t + 1] = ebase + e0 + h0;
  int n0 = (b << BUCKET_SHIFT) + 2 * t;
  if (n0 < N) row_off[n0] = ebase + e0;
  if (n0 + 1 < N) row_off[n0 + 1] = ebase + e0 + h0;
  __syncthreads();
  for (int i = ebase + t; i < eend; i += 256) {
    int pk = epk1[i];
    int p = atomicAdd(&cur[pk >> 19], 1);
    epk[p] = pk;
  }
}

// One wave per node; lane = channel. Z[n][0..63]=basis0 acc, [64..127]=basis1.
__global__ void __launch_bounds__(256) k_aggregate(
    const float* __restrict__ x, const int* __restrict__ row_off,
    const int* __restrict__ epk, const float* __restrict__ comp,
    float* __restrict__ Z, int N) {
  __shared__ float s_comp[8];
  if (threadIdx.x < 8) s_comp[threadIdx.x] = comp[threadIdx.x];
  __syncthreads();
  int node = blockIdx.x * NODES_PER_BLOCK + (threadIdx.x >> 6);
  int lane = threadIdx.x & 63;
  if (node >= N) return;
  int beg = row_off[node], end = row_off[node + 1];
  float z0 = 0.f, z1 = 0.f;
  int e = beg;
  for (; e + 1 < end; e += 2) {
    int pk0 = epk[e], pk1 = epk[e + 1];
    int s0 = pk0 & 0x1FFFF, r0 = (pk0 >> 17) & 3;
    int s1 = pk1 & 0x1FFFF, r1 = (pk1 >> 17) & 3;
    float xv0 = x[(size_t)s0 * 64 + lane];
    float xv1 = x[(size_t)s1 * 64 + lane];
    z0 = fmaf(s_comp[r0 * 2 + 0], xv0, z0);
    z1 = fmaf(s_comp[r0 * 2 + 1], xv0, z1);
    z0 = fmaf(s_comp[r1 * 2 + 0], xv1, z0);
    z1 = fmaf(s_comp[r1 * 2 + 1], xv1, z1);
  }
  if (e < end) {
    int pk = epk[e];
    int s = pk & 0x1FFFF, r = (pk >> 17) & 3;
    float xv = x[(size_t)s * 64 + lane];
    z0 = fmaf(s_comp[r * 2 + 0], xv, z0);
    z1 = fmaf(s_comp[r * 2 + 1], xv, z1);
  }
  Z[(size_t)node * 128 + lane] = z0;
  Z[(size_t)node * 128 + 64 + lane] = z1;
}

// out[n,:] = relu( Z[n,0:128] @ bases(128x64) + x[n,:] @ loop_w(64x64) + bias )
__global__ void __launch_bounds__(256) k_gemm(
    const float* __restrict__ Z, const float* __restrict__ x,
    const float* __restrict__ bases, const float* __restrict__ loopw,
    const float* __restrict__ bias, float* __restrict__ out, int N) {
  __shared__ float sW[64 * 64];
  __shared__ float sA[64 * 64];
  int t = threadIdx.x;
  int tx = t & 15, ty = t >> 4;
  int row0 = blockIdx.x * 64;
  float acc[4][4] = {{0.f, 0.f, 0.f, 0.f}};

  for (int ch = 0; ch < 3; ++ch) {
    __syncthreads();
    const float4* wsrc = (ch < 2) ? ((const float4*)bases + (size_t)ch * 1024)
                                  : (const float4*)loopw;
#pragma unroll
    for (int q = 0; q < 4; ++q) ((float4*)sW)[t + q * 256] = wsrc[t + q * 256];
#pragma unroll
    for (int q = 0; q < 4; ++q) {
      int i = t + q * 256;
      int lr = i >> 4;
      int lc = (i & 15) * 4;
      int grow = row0 + lr;
      float4 v = make_float4(0.f, 0.f, 0.f, 0.f);
      if (grow < N) {
        const float* g;
        if (ch == 0)      g = Z + (size_t)grow * 128 + lc;
        else if (ch == 1) g = Z + (size_t)grow * 128 + 64 + lc;
        else              g = x + (size_t)grow * 64 + lc;
        v = *(const float4*)g;
      }
      int swc = lc ^ (((lr >> 2) & 3) << 4);
      *(float4*)(sA + lr * 64 + swc) = v;
    }
    __syncthreads();
    int swk_base = (ty & 3) << 4;
#pragma unroll 4
    for (int k = 0; k < 64; ++k) {
      float4 wv = *(const float4*)(sW + k * 64 + tx * 4);
      int kk = k ^ swk_base;
      float a0 = sA[(ty * 4 + 0) * 64 + kk];
      float a1 = sA[(ty * 4 + 1) * 64 + kk];
      float a2 = sA[(ty * 4 + 2) * 64 + kk];
      float a3 = sA[(ty * 4 + 3) * 64 + kk];
      acc[0][0] = fmaf(a0, wv.x, acc[0][0]);
      acc[0][1] = fmaf(a0, wv.y, acc[0][1]);
      acc[0][2] = fmaf(a0, wv.z, acc[0][2]);
      acc[0][3] = fmaf(a0, wv.w, acc[0][3]);
      acc[1][0] = fmaf(a1, wv.x, acc[1][0]);
      acc[1][1] = fmaf(a1, wv.y, acc[1][1]);
      acc[1][2] = fmaf(a1, wv.z, acc[1][2]);
      acc[1][3] = fmaf(a1, wv.w, acc[1][3]);
      acc[2][0] = fmaf(a2, wv.x, acc[2][0]);
      acc[2][1] = fmaf(a2, wv.y, acc[2][1]);
      acc[2][2] = fmaf(a2, wv.z, acc[2][2]);
      acc[2][3] = fmaf(a2, wv.w, acc[2][3]);
      acc[3][0] = fmaf(a3, wv.x, acc[3][0]);
      acc[3][1] = fmaf(a3, wv.y, acc[3][1]);
      acc[3][2] = fmaf(a3, wv.z, acc[3][2]);
      acc[3][3] = fmaf(a3, wv.w, acc[3][3]);
    }
  }
  float4 bv = *(const float4*)(bias + tx * 4);
#pragma unroll
  for (int j = 0; j < 4; ++j) {
    int r = row0 + ty * 4 + j;
    if (r < N) {
      float4 o;
      o.x = fmaxf(acc[j][0] + bv.x, 0.f);
      o.y = fmaxf(acc[j][1] + bv.y, 0.f);
      o.z = fmaxf(acc[j][2] + bv.z, 0.f);
      o.w = fmaxf(acc[j][3] + bv.w, 0.f);
      *(float4*)(out + (size_t)r * 64 + tx * 4) = o;
    }
  }
}

__global__ void __launch_bounds__(256) k_pred(
    const float* __restrict__ x, const float* __restrict__ pw,
    const float* __restrict__ pb, float* __restrict__ out, int N) {
  int node = blockIdx.x * NODES_PER_BLOCK + (threadIdx.x >> 6);
  int lane = threadIdx.x & 63;
  if (node >= N) return;
  float v = x[(size_t)node * 64 + lane] * pw[lane];
#pragma unroll
  for (int off = 32; off > 0; off >>= 1) v += __shfl_down(v, off, 64);
  if (lane == 0) {
    float logit = v + pb[0];
    out[node] = 1.f / (1.f + expf(-logit));
  }
}

extern "C" void kernel_launch(void* const* d_in, const int* in_sizes, int n_in,
                              void* d_out, int out_size, void* d_ws, size_t ws_size,
                              hipStream_t stream) {
  const float* features = (const float*)d_in[0];
  const int* src = (const int*)d_in[1];
  const int* dst = (const int*)d_in[2];
  const int* et  = (const int*)d_in[3];
  const float* bases[3] = {(const float*)d_in[4], (const float*)d_in[8],  (const float*)d_in[12]};
  const float* comp[3]  = {(const float*)d_in[5], (const float*)d_in[9],  (const float*)d_in[13]};
  const float* loopw[3] = {(const float*)d_in[6], (const float*)d_in[10], (const float*)d_in[14]};
  const float* biasp[3] = {(const float*)d_in[7], (const float*)d_in[11], (const float*)d_in[15]};
  const float* pred_w = (const float*)d_in[16];
  const float* pred_b = (const float*)d_in[17];

  const int N = in_sizes[0] / 64;   // 100000
  const int E = in_sizes[1];        // 1600000

  char* ws = (char*)d_ws;
  size_t off = 0;
  auto take = [&](size_t bytes) {
    char* p = ws + off;
    off += (bytes + 255) & ~(size_t)255;
    return p;
  };
  int*   row_off     = (int*)  take((size_t)(N + 1) * 4);
  int*   H           = (int*)  take((size_t)NBLK1 * NB1 * 4);
  int*   total       = (int*)  take((size_t)NB1 * 4);
  int*   bucket_base = (int*)  take((size_t)(NB1 + 1) * 4);
  int*   epk         = (int*)  take((size_t)E * 4);
  float* Zb          = (float*)take((size_t)N * 128 * 4);
  float* xA          = (float*)take((size_t)N * 64 * 4);
  float* xB          = (float*)take((size_t)N * 64 * 4);
  int*   epk1        = (int*)Zb;   // alias: Z is dead during CSR build
  (void)ws_size;

  // ---- CSR build: 2-level counting sort, no global atomics
  int chunk = (E + NBLK1 - 1) / NBLK1;
  k_l1hist  <<<NBLK1, 256, 0, stream>>>(dst, H, E, chunk);
  k_colscan <<<NB1,   256, 0, stream>>>(H, total);
  k_basescan<<<1,     256, 0, stream>>>(total, bucket_base, row_off, N);
  k_scatter1<<<NBLK1, 256, 0, stream>>>(src, dst, et, H, bucket_base, epk1, E, chunk);
  k_bucket  <<<NB1,   256, 0, stream>>>(epk1, bucket_base, epk, row_off, N);

  // ---- 3 RGCN layers
  const float* xin = features;
  float* outs[3] = {xA, xB, xA};
  int agg_grid = (N + NODES_PER_BLOCK - 1) / NODES_PER_BLOCK;
  int gemm_grid = (N + 63) / 64;
  for (int l = 0; l < 3; ++l) {
    k_aggregate<<<agg_grid, 256, 0, stream>>>(xin, row_off, epk, comp[l], Zb, N);
    k_gemm<<<gemm_grid, 256, 0, stream>>>(Zb, xin, bases[l], loopw[l], biasp[l], outs[l], N);
    xin = outs[l];
  }

  // ---- predictor + sigmoid
  k_pred<<<agg_grid, 256, 0, stream>>>(xA, pred_w, pred_b, (float*)d_out, N);
}

// Round 4
// 417.237 us; speedup vs baseline: 1.7702x; 1.1916x over previous
//
#include <hip/hip_runtime.h>
#include <hip/hip_bf16.h>
#include <hip/hip_fp16.h>

// RGCN: 3 layers of basis-decomposed relational graph conv + predictor.
// CSR build via 2-level counting sort (NO global atomics).
// Aggregation gathers x[src] in FP16 (halves gather traffic vs fp32; fp32
// accum; fp16's 11-bit mantissa keeps absmax ~5e-3, bf16's 8-bit failed).
// Per layer:
//   Z[n, b*64+i] = sum_{e: dst=n} comp[et_e, b] * xq[src_e, i]  (wave/node)
//   out = relu([Z | x] @ [bases ; loop_w] + bias)               (tiled GEMM,
//        epilogue also emits fp16 copy of out for the next layer's gather)
// Final: sigmoid(x @ pred_w + pred_b).

#define NODES_PER_BLOCK 4
#define NB1 196        // ceil(100000/512) coarse buckets
#define NBLK1 256      // L1 partition blocks
#define BUCKET_SHIFT 9 // 512 nodes per bucket

typedef unsigned short ushort_t;

__device__ inline ushort_t f2h(float f) {
  __half h = __float2half_rn(f);
  return *(ushort_t*)&h;
}
__device__ inline float h2f(ushort_t u) {
  __half h = *(__half*)&u;
  return __half2float(h);
}

// inclusive scan of one int per thread across a 256-thread block
__device__ inline int block_incl_scan_256(int v, int* wsums) {
  int lane = threadIdx.x & 63, wid = threadIdx.x >> 6;
  int s = v;
#pragma unroll
  for (int off = 1; off < 64; off <<= 1) {
    int u = __shfl_up(s, off, 64);
    if (lane >= off) s += u;
  }
  if (lane == 63) wsums[wid] = s;
  __syncthreads();
  if (threadIdx.x == 0) {
    int a = 0;
#pragma unroll
    for (int w = 0; w < 4; ++w) { int t = wsums[w]; wsums[w] = a; a += t; }
  }
  __syncthreads();
  return s + wsums[wid];
}

// ---- L1 pass a: per-block LDS histogram over 196 coarse buckets
__global__ void __launch_bounds__(256) k_l1hist(const int* __restrict__ dst,
                                                int* __restrict__ H, int E, int chunk) {
  __shared__ int h[NB1];
  int t = threadIdx.x;
  if (t < NB1) h[t] = 0;
  __syncthreads();
  int beg = blockIdx.x * chunk;
  int end = min(beg + chunk, E);
  for (int i = beg + t; i < end; i += 256) atomicAdd(&h[dst[i] >> BUCKET_SHIFT], 1);
  __syncthreads();
  if (t < NB1) H[blockIdx.x * NB1 + t] = h[t];
}

// ---- L1 pass b: scan each bucket's column of H -> excl offsets + totals
__global__ void __launch_bounds__(256) k_colscan(int* __restrict__ H,
                                                 int* __restrict__ total) {
  __shared__ int wsums[4];
  int b = blockIdx.x;
  int t = threadIdx.x;
  int v = H[t * NB1 + b];
  int s = block_incl_scan_256(v, wsums);
  H[t * NB1 + b] = s - v;
  if (t == 255) total[b] = s;
}

// ---- L1 pass c: scan bucket totals -> bucket_base, row_off[N]=E
__global__ void __launch_bounds__(256) k_basescan(const int* __restrict__ total,
                                                  int* __restrict__ bucket_base,
                                                  int* __restrict__ row_off, int N) {
  __shared__ int wsums[4];
  int t = threadIdx.x;
  int v = (t < NB1) ? total[t] : 0;
  int s = block_incl_scan_256(v, wsums);
  if (t < NB1) bucket_base[t] = s - v;
  if (t == 255) { bucket_base[NB1] = s; row_off[N] = s; }
}

// ---- L1 pass d: scatter edges into bucket-partitioned epk1 via LDS cursors
__global__ void __launch_bounds__(256) k_scatter1(
    const int* __restrict__ src, const int* __restrict__ dst,
    const int* __restrict__ et, const int* __restrict__ H,
    const int* __restrict__ bucket_base, int* __restrict__ epk1,
    int E, int chunk) {
  __shared__ int cur[NB1];
  int t = threadIdx.x;
  if (t < NB1) cur[t] = bucket_base[t] + H[blockIdx.x * NB1 + t];
  __syncthreads();
  int beg = blockIdx.x * chunk;
  int end = min(beg + chunk, E);
  for (int i = beg + t; i < end; i += 256) {
    int d = dst[i];
    int b = d >> BUCKET_SHIFT;
    int p = atomicAdd(&cur[b], 1);
    epk1[p] = src[i] | (et[i] << 17) | ((d & 511) << 19);
  }
}

// ---- L2: per-bucket exact sort by dst_local (512 bins) -> epk + row_off
__global__ void __launch_bounds__(256) k_bucket(
    const int* __restrict__ epk1, const int* __restrict__ bucket_base,
    int* __restrict__ epk, int* __restrict__ row_off, int N) {
  __shared__ int hist[512];
  __shared__ int cur[512];
  __shared__ int wsums[4];
  int b = blockIdx.x;
  int t = threadIdx.x;
  int ebase = bucket_base[b], eend = bucket_base[b + 1];
  hist[t] = 0; hist[t + 256] = 0;
  __syncthreads();
  for (int i = ebase + t; i < eend; i += 256) atomicAdd(&hist[epk1[i] >> 19], 1);
  __syncthreads();
  int h0 = hist[2 * t], h1 = hist[2 * t + 1];
  int pair = h0 + h1;
  int incl = block_incl_scan_256(pair, wsums);
  int e0 = incl - pair;
  cur[2 * t] = ebase + e0;
  cur[2 * t + 1] = ebase + e0 + h0;
  int n0 = (b << BUCKET_SHIFT) + 2 * t;
  if (n0 < N) row_off[n0] = ebase + e0;
  if (n0 + 1 < N) row_off[n0 + 1] = ebase + e0 + h0;
  __syncthreads();
  for (int i = ebase + t; i < eend; i += 256) {
    int pk = epk1[i];
    int p = atomicAdd(&cur[pk >> 19], 1);
    epk[p] = pk;
  }
}

// ---- quantize fp32 -> fp16 (RTNE), vectorized
__global__ void __launch_bounds__(256) k_quant(const float* __restrict__ in,
                                               ushort_t* __restrict__ out, int n4) {
  int i = blockIdx.x * blockDim.x + threadIdx.x;
  if (i < n4) {
    float4 v = ((const float4*)in)[i];
    ushort4 q;
    q.x = f2h(v.x); q.y = f2h(v.y);
    q.z = f2h(v.z); q.w = f2h(v.w);
    ((ushort4*)out)[i] = q;
  }
}

// One wave per node; lane = channel. Gathers fp16 rows (128B/edge).
// 4-wide edge unroll for memory-level parallelism (latency-bound gather).
__global__ void __launch_bounds__(256) k_aggregate(
    const ushort_t* __restrict__ xq, const int* __restrict__ row_off,
    const int* __restrict__ epk, const float* __restrict__ comp,
    float* __restrict__ Z, int N) {
  __shared__ float s_comp[8];
  if (threadIdx.x < 8) s_comp[threadIdx.x] = comp[threadIdx.x];
  __syncthreads();
  int node = blockIdx.x * NODES_PER_BLOCK + (threadIdx.x >> 6);
  int lane = threadIdx.x & 63;
  if (node >= N) return;
  int beg = row_off[node], end = row_off[node + 1];
  float z0 = 0.f, z1 = 0.f;
  int e = beg;
  for (; e + 3 < end; e += 4) {
    int pk0 = epk[e], pk1 = epk[e + 1], pk2 = epk[e + 2], pk3 = epk[e + 3];
    int s0 = pk0 & 0x1FFFF, r0 = (pk0 >> 17) & 3;
    int s1 = pk1 & 0x1FFFF, r1 = (pk1 >> 17) & 3;
    int s2 = pk2 & 0x1FFFF, r2 = (pk2 >> 17) & 3;
    int s3 = pk3 & 0x1FFFF, r3 = (pk3 >> 17) & 3;
    float x0 = h2f(xq[(size_t)s0 * 64 + lane]);
    float x1 = h2f(xq[(size_t)s1 * 64 + lane]);
    float x2 = h2f(xq[(size_t)s2 * 64 + lane]);
    float x3 = h2f(xq[(size_t)s3 * 64 + lane]);
    z0 = fmaf(s_comp[r0 * 2 + 0], x0, z0);
    z1 = fmaf(s_comp[r0 * 2 + 1], x0, z1);
    z0 = fmaf(s_comp[r1 * 2 + 0], x1, z0);
    z1 = fmaf(s_comp[r1 * 2 + 1], x1, z1);
    z0 = fmaf(s_comp[r2 * 2 + 0], x2, z0);
    z1 = fmaf(s_comp[r2 * 2 + 1], x2, z1);
    z0 = fmaf(s_comp[r3 * 2 + 0], x3, z0);
    z1 = fmaf(s_comp[r3 * 2 + 1], x3, z1);
  }
  for (; e < end; ++e) {
    int pk = epk[e];
    int s = pk & 0x1FFFF, r = (pk >> 17) & 3;
    float xv = h2f(xq[(size_t)s * 64 + lane]);
    z0 = fmaf(s_comp[r * 2 + 0], xv, z0);
    z1 = fmaf(s_comp[r * 2 + 1], xv, z1);
  }
  Z[(size_t)node * 128 + lane] = z0;
  Z[(size_t)node * 128 + 64 + lane] = z1;
}

// out[n,:] = relu( Z[n,0:128] @ bases(128x64) + x[n,:] @ loop_w(64x64) + bias )
// Epilogue optionally emits fp16 copy (qout) for the next layer's gather.
__global__ void __launch_bounds__(256) k_gemm(
    const float* __restrict__ Z, const float* __restrict__ x,
    const float* __restrict__ bases, const float* __restrict__ loopw,
    const float* __restrict__ bias, float* __restrict__ out,
    ushort_t* __restrict__ qout, int N) {
  __shared__ float sW[64 * 64];
  __shared__ float sA[64 * 64];
  int t = threadIdx.x;
  int tx = t & 15, ty = t >> 4;
  int row0 = blockIdx.x * 64;
  float acc[4][4] = {{0.f, 0.f, 0.f, 0.f}};

  for (int ch = 0; ch < 3; ++ch) {
    __syncthreads();
    const float4* wsrc = (ch < 2) ? ((const float4*)bases + (size_t)ch * 1024)
                                  : (const float4*)loopw;
#pragma unroll
    for (int q = 0; q < 4; ++q) ((float4*)sW)[t + q * 256] = wsrc[t + q * 256];
#pragma unroll
    for (int q = 0; q < 4; ++q) {
      int i = t + q * 256;
      int lr = i >> 4;
      int lc = (i & 15) * 4;
      int grow = row0 + lr;
      float4 v = make_float4(0.f, 0.f, 0.f, 0.f);
      if (grow < N) {
        const float* g;
        if (ch == 0)      g = Z + (size_t)grow * 128 + lc;
        else if (ch == 1) g = Z + (size_t)grow * 128 + 64 + lc;
        else              g = x + (size_t)grow * 64 + lc;
        v = *(const float4*)g;
      }
      int swc = lc ^ (((lr >> 2) & 3) << 4);
      *(float4*)(sA + lr * 64 + swc) = v;
    }
    __syncthreads();
    int swk_base = (ty & 3) << 4;
#pragma unroll 4
    for (int k = 0; k < 64; ++k) {
      float4 wv = *(const float4*)(sW + k * 64 + tx * 4);
      int kk = k ^ swk_base;
      float a0 = sA[(ty * 4 + 0) * 64 + kk];
      float a1 = sA[(ty * 4 + 1) * 64 + kk];
      float a2 = sA[(ty * 4 + 2) * 64 + kk];
      float a3 = sA[(ty * 4 + 3) * 64 + kk];
      acc[0][0] = fmaf(a0, wv.x, acc[0][0]);
      acc[0][1] = fmaf(a0, wv.y, acc[0][1]);
      acc[0][2] = fmaf(a0, wv.z, acc[0][2]);
      acc[0][3] = fmaf(a0, wv.w, acc[0][3]);
      acc[1][0] = fmaf(a1, wv.x, acc[1][0]);
      acc[1][1] = fmaf(a1, wv.y, acc[1][1]);
      acc[1][2] = fmaf(a1, wv.z, acc[1][2]);
      acc[1][3] = fmaf(a1, wv.w, acc[1][3]);
      acc[2][0] = fmaf(a2, wv.x, acc[2][0]);
      acc[2][1] = fmaf(a2, wv.y, acc[2][1]);
      acc[2][2] = fmaf(a2, wv.z, acc[2][2]);
      acc[2][3] = fmaf(a2, wv.w, acc[2][3]);
      acc[3][0] = fmaf(a3, wv.x, acc[3][0]);
      acc[3][1] = fmaf(a3, wv.y, acc[3][1]);
      acc[3][2] = fmaf(a3, wv.z, acc[3][2]);
      acc[3][3] = fmaf(a3, wv.w, acc[3][3]);
    }
  }
  float4 bv = *(const float4*)(bias + tx * 4);
#pragma unroll
  for (int j = 0; j < 4; ++j) {
    int r = row0 + ty * 4 + j;
    if (r < N) {
      float4 o;
      o.x = fmaxf(acc[j][0] + bv.x, 0.f);
      o.y = fmaxf(acc[j][1] + bv.y, 0.f);
      o.z = fmaxf(acc[j][2] + bv.z, 0.f);
      o.w = fmaxf(acc[j][3] + bv.w, 0.f);
      *(float4*)(out + (size_t)r * 64 + tx * 4) = o;
      if (qout) {
        ushort4 q;
        q.x = f2h(o.x); q.y = f2h(o.y);
        q.z = f2h(o.z); q.w = f2h(o.w);
        *(ushort4*)(qout + (size_t)r * 64 + tx * 4) = q;
      }
    }
  }
}

__global__ void __launch_bounds__(256) k_pred(
    const float* __restrict__ x, const float* __restrict__ pw,
    const float* __restrict__ pb, float* __restrict__ out, int N) {
  int node = blockIdx.x * NODES_PER_BLOCK + (threadIdx.x >> 6);
  int lane = threadIdx.x & 63;
  if (node >= N) return;
  float v = x[(size_t)node * 64 + lane] * pw[lane];
#pragma unroll
  for (int off = 32; off > 0; off >>= 1) v += __shfl_down(v, off, 64);
  if (lane == 0) {
    float logit = v + pb[0];
    out[node] = 1.f / (1.f + expf(-logit));
  }
}

extern "C" void kernel_launch(void* const* d_in, const int* in_sizes, int n_in,
                              void* d_out, int out_size, void* d_ws, size_t ws_size,
                              hipStream_t stream) {
  const float* features = (const float*)d_in[0];
  const int* src = (const int*)d_in[1];
  const int* dst = (const int*)d_in[2];
  const int* et  = (const int*)d_in[3];
  const float* bases[3] = {(const float*)d_in[4], (const float*)d_in[8],  (const float*)d_in[12]};
  const float* comp[3]  = {(const float*)d_in[5], (const float*)d_in[9],  (const float*)d_in[13]};
  const float* loopw[3] = {(const float*)d_in[6], (const float*)d_in[10], (const float*)d_in[14]};
  const float* biasp[3] = {(const float*)d_in[7], (const float*)d_in[11], (const float*)d_in[15]};
  const float* pred_w = (const float*)d_in[16];
  const float* pred_b = (const float*)d_in[17];

  const int N = in_sizes[0] / 64;   // 100000
  const int E = in_sizes[1];        // 1600000

  char* ws = (char*)d_ws;
  size_t off = 0;
  auto take = [&](size_t bytes) {
    char* p = ws + off;
    off += (bytes + 255) & ~(size_t)255;
    return p;
  };
  int*      row_off     = (int*)     take((size_t)(N + 1) * 4);
  int*      H           = (int*)     take((size_t)NBLK1 * NB1 * 4);
  int*      total       = (int*)     take((size_t)NB1 * 4);
  int*      bucket_base = (int*)     take((size_t)(NB1 + 1) * 4);
  int*      epk         = (int*)     take((size_t)E * 4);
  float*    Zb          = (float*)   take((size_t)N * 128 * 4);
  float*    xA          = (float*)   take((size_t)N * 64 * 4);
  float*    xB          = (float*)   take((size_t)N * 64 * 4);
  ushort_t* xq          = (ushort_t*)take((size_t)N * 64 * 2);
  int*      epk1        = (int*)Zb;   // alias: Z is dead during CSR build
  (void)ws_size;

  // ---- CSR build: 2-level counting sort, no global atomics
  int chunk = (E + NBLK1 - 1) / NBLK1;
  k_l1hist  <<<NBLK1, 256, 0, stream>>>(dst, H, E, chunk);
  k_colscan <<<NB1,   256, 0, stream>>>(H, total);
  k_basescan<<<1,     256, 0, stream>>>(total, bucket_base, row_off, N);
  k_scatter1<<<NBLK1, 256, 0, stream>>>(src, dst, et, H, bucket_base, epk1, E, chunk);
  k_bucket  <<<NB1,   256, 0, stream>>>(epk1, bucket_base, epk, row_off, N);

  // ---- quantize input features to fp16 for the gather
  k_quant<<<(N * 16 + 255) / 256, 256, 0, stream>>>(features, xq, N * 16);

  // ---- 3 RGCN layers (xq always holds fp16 of current layer input;
  //      gemm(l) overwrites it with layer-l output AFTER aggregate(l) read it)
  const float* xin = features;
  float* outs[3] = {xA, xB, xA};
  int agg_grid = (N + NODES_PER_BLOCK - 1) / NODES_PER_BLOCK;
  int gemm_grid = (N + 63) / 64;
  for (int l = 0; l < 3; ++l) {
    k_aggregate<<<agg_grid, 256, 0, stream>>>(xq, row_off, epk, comp[l], Zb, N);
    k_gemm<<<gemm_grid, 256, 0, stream>>>(Zb, xin, bases[l], loopw[l], biasp[l],
                                          outs[l], (l < 2) ? xq : nullptr, N);
    xin = outs[l];
  }

  // ---- predictor + sigmoid
  k_pred<<<agg_grid, 256, 0, stream>>>(xA, pred_w, pred_b, (float*)d_out, N);
}